// Round 1
// baseline (915.981 us; speedup 1.0000x reference)
//
#include <hip/hip_runtime.h>
#include <hip/hip_bf16.h>

#define N_USERS 100000
#define N_ITEMS 200000
#define N_NODES 300000
#define DIM 64

#define TOT_ELEMS ((size_t)N_NODES * DIM)          // 19,200,000 floats
#define TOT_F4    (TOT_ELEMS / 4)                  // 4,800,000
#define USER_F4   (((size_t)N_USERS * DIM) / 4)    // 1,600,000

#define BROWS 512
#define NBUCKET ((N_NODES + BROWS - 1) / BROWS)    // 586
#define EPT 32
#define EDGES_PER_BLOCK (EPT * 256)                // 8192

__device__ __forceinline__ float bf2f(unsigned short u) {
    return __uint_as_float((unsigned int)u << 16);
}
__device__ __forceinline__ unsigned short f2bf(float f) {
    __hip_bfloat16 h = __float2bfloat16(f);   // RNE
    return *reinterpret_cast<unsigned short*>(&h);
}

// ---------- init: xh = bf16(concat(user,item)) ----------
__global__ void init_kernel(const float4* __restrict__ user,
                            const float4* __restrict__ item,
                            ushort4* __restrict__ xh) {
    size_t i = (size_t)blockIdx.x * blockDim.x + threadIdx.x;
    if (i >= TOT_F4) return;
    float4 v = (i < USER_F4) ? user[i] : item[i - USER_F4];
    ushort4 h;
    h.x = f2bf(v.x); h.y = f2bf(v.y); h.z = f2bf(v.z); h.w = f2bf(v.w);
    xh[i] = h;
}

// ---------- bucket-level histogram (586 counters, cache-resident) ----------
__global__ void zero_buckets_kernel(int* __restrict__ bucket_count) {
    int i = blockIdx.x * blockDim.x + threadIdx.x;
    if (i < NBUCKET) bucket_count[i] = 0;
}

__global__ void bucket_hist_kernel(const int* __restrict__ rows,
                                   int* __restrict__ bucket_count, int nnz) {
    __shared__ int h[NBUCKET];
    int t = threadIdx.x;
    size_t base = (size_t)blockIdx.x * EDGES_PER_BLOCK;
    for (int i = t; i < NBUCKET; i += 256) h[i] = 0;
    __syncthreads();
    #pragma unroll 4
    for (int k = 0; k < EPT; ++k) {
        size_t e = base + (size_t)k * 256 + t;
        if (e < (size_t)nnz) atomicAdd(&h[rows[e] >> 9], 1);
    }
    __syncthreads();
    for (int i = t; i < NBUCKET; i += 256) {
        int c = h[i];
        if (c) atomicAdd(&bucket_count[i], c);
    }
}

// exclusive scan of bucket counts -> bucket_base[0..NBUCKET], seed bucket_cursor
__global__ void bucket_scan_kernel(const int* __restrict__ bucket_count,
                                   int* __restrict__ bucket_base,
                                   int* __restrict__ bucket_cursor, int nnz) {
    __shared__ int s[1024];
    int t = threadIdx.x;
    int orig = (t < NBUCKET) ? bucket_count[t] : 0;
    s[t] = orig;
    __syncthreads();
    for (int off = 1; off < 1024; off <<= 1) {
        int v = (t >= off) ? s[t - off] : 0;
        __syncthreads();
        s[t] += v;
        __syncthreads();
    }
    if (t < NBUCKET) {
        int excl = s[t] - orig;
        bucket_base[t]   = excl;
        bucket_cursor[t] = excl;
    }
    if (t == 0) bucket_base[NBUCKET] = nnz;
}

// ---------- Pass A: bin edges into bucket ranges ----------
// payload: (.x = localrow<<19 | col, .y = val bits)
__global__ void binA_kernel(const int* __restrict__ rows,
                            const int* __restrict__ cols,
                            const float* __restrict__ vals,
                            int* __restrict__ bucket_cursor,
                            int2* __restrict__ binned,
                            int nnz) {
    __shared__ int h[NBUCKET];
    int t = threadIdx.x;
    size_t base = (size_t)blockIdx.x * EDGES_PER_BLOCK;
    for (int i = t; i < NBUCKET; i += 256) h[i] = 0;
    __syncthreads();
    #pragma unroll 4
    for (int k = 0; k < EPT; ++k) {
        size_t e = base + (size_t)k * 256 + t;
        if (e < (size_t)nnz) atomicAdd(&h[rows[e] >> 9], 1);
    }
    __syncthreads();
    for (int i = t; i < NBUCKET; i += 256) {
        int c = h[i];
        h[i] = (c > 0) ? atomicAdd(&bucket_cursor[i], c) : 0;
    }
    __syncthreads();
    #pragma unroll 4
    for (int k = 0; k < EPT; ++k) {
        size_t e = base + (size_t)k * 256 + t;
        if (e < (size_t)nnz) {
            int r = rows[e];
            int pos = atomicAdd(&h[r >> 9], 1);
            binned[pos] = make_int2(((r & (BROWS - 1)) << 19) | cols[e],
                                    __float_as_int(vals[e]));
        }
    }
}

// ---------- Pass B: per-row histogram + scan -> row_ptr, then permute ----------
__global__ void binB_kernel(const int* __restrict__ bucket_base,
                            const int2* __restrict__ binned,
                            int2* __restrict__ sorted,
                            int* __restrict__ row_ptr,
                            int nnz) {
    __shared__ int cnt[BROWS];
    __shared__ int cur[BROWS];
    __shared__ int s[256];
    int b = blockIdx.x, t = threadIdx.x;
    int beg = bucket_base[b];
    int end = bucket_base[b + 1];
    int row0 = b * BROWS;
    for (int i = t; i < BROWS; i += 256) cnt[i] = 0;
    __syncthreads();
    // per-row histogram of this bucket's edges
    for (int idx = beg + t; idx < end; idx += 256) {
        int lr = ((unsigned)binned[idx].x) >> 19;
        atomicAdd(&cnt[lr], 1);
    }
    __syncthreads();
    // exclusive scan of 512 counts (2 per thread)
    int c0 = cnt[2 * t], c1 = cnt[2 * t + 1];
    int local = c0 + c1;
    s[t] = local;
    __syncthreads();
    for (int off = 1; off < 256; off <<= 1) {
        int v = (t >= off) ? s[t - off] : 0;
        __syncthreads();
        s[t] += v;
        __syncthreads();
    }
    int excl = beg + s[t] - local;
    int r0 = row0 + 2 * t;
    if (r0 < N_NODES)     row_ptr[r0]     = excl;
    if (r0 + 1 < N_NODES) row_ptr[r0 + 1] = excl + c0;
    cur[2 * t]     = excl;
    cur[2 * t + 1] = excl + c0;
    __syncthreads();
    // permute to exact CSR order
    for (int idx = beg + t; idx < end; idx += 256) {
        int2 e = binned[idx];
        int lr  = ((unsigned)e.x) >> 19;
        int col = e.x & 0x7FFFF;
        int pos = atomicAdd(&cur[lr], 1);
        sorted[pos] = make_int2(col, e.y);
    }
    if (b == 0 && t == 0) row_ptr[N_NODES] = nnz;
}

// ---------- row accumulate: one wave per row, lane = dim ----------
// Cross-lane broadcast via v_readlane (VALU/SALU) instead of ds_bpermute:
// j is wave-uniform, so readlane == shfl but stays off the shared LDS pipe,
// and col/val land in SGPRs (scalar gather base, SGPR fma operand).
__device__ __forceinline__ float row_accum(int beg, int end, int d,
                                           const int2* __restrict__ sorted,
                                           const unsigned short* __restrict__ srch) {
    float acc = 0.f;
    for (int base = beg; base < end; base += 64) {
        int rem = end - base;
        int cnt = rem > 64 ? 64 : rem;
        int c_l = 0;
        int v_i = 0;
        if (base + d < end) {
            int2 e = sorted[base + d];
            c_l = e.x;
            v_i = e.y;
        }
        int j = 0;
        for (; j + 8 <= cnt; j += 8) {
            int c0 = __builtin_amdgcn_readlane(c_l, j + 0);
            int c1 = __builtin_amdgcn_readlane(c_l, j + 1);
            int c2 = __builtin_amdgcn_readlane(c_l, j + 2);
            int c3 = __builtin_amdgcn_readlane(c_l, j + 3);
            int c4 = __builtin_amdgcn_readlane(c_l, j + 4);
            int c5 = __builtin_amdgcn_readlane(c_l, j + 5);
            int c6 = __builtin_amdgcn_readlane(c_l, j + 6);
            int c7 = __builtin_amdgcn_readlane(c_l, j + 7);
            float s0 = bf2f(srch[(size_t)c0 * DIM + d]);
            float s1 = bf2f(srch[(size_t)c1 * DIM + d]);
            float s2 = bf2f(srch[(size_t)c2 * DIM + d]);
            float s3 = bf2f(srch[(size_t)c3 * DIM + d]);
            float s4 = bf2f(srch[(size_t)c4 * DIM + d]);
            float s5 = bf2f(srch[(size_t)c5 * DIM + d]);
            float s6 = bf2f(srch[(size_t)c6 * DIM + d]);
            float s7 = bf2f(srch[(size_t)c7 * DIM + d]);
            float v0 = __uint_as_float(__builtin_amdgcn_readlane(v_i, j + 0));
            float v1 = __uint_as_float(__builtin_amdgcn_readlane(v_i, j + 1));
            float v2 = __uint_as_float(__builtin_amdgcn_readlane(v_i, j + 2));
            float v3 = __uint_as_float(__builtin_amdgcn_readlane(v_i, j + 3));
            float v4 = __uint_as_float(__builtin_amdgcn_readlane(v_i, j + 4));
            float v5 = __uint_as_float(__builtin_amdgcn_readlane(v_i, j + 5));
            float v6 = __uint_as_float(__builtin_amdgcn_readlane(v_i, j + 6));
            float v7 = __uint_as_float(__builtin_amdgcn_readlane(v_i, j + 7));
            acc += v0 * s0; acc += v1 * s1; acc += v2 * s2; acc += v3 * s3;
            acc += v4 * s4; acc += v5 * s5; acc += v6 * s6; acc += v7 * s7;
        }
        for (; j + 4 <= cnt; j += 4) {
            int c0 = __builtin_amdgcn_readlane(c_l, j + 0);
            int c1 = __builtin_amdgcn_readlane(c_l, j + 1);
            int c2 = __builtin_amdgcn_readlane(c_l, j + 2);
            int c3 = __builtin_amdgcn_readlane(c_l, j + 3);
            float s0 = bf2f(srch[(size_t)c0 * DIM + d]);
            float s1 = bf2f(srch[(size_t)c1 * DIM + d]);
            float s2 = bf2f(srch[(size_t)c2 * DIM + d]);
            float s3 = bf2f(srch[(size_t)c3 * DIM + d]);
            float v0 = __uint_as_float(__builtin_amdgcn_readlane(v_i, j + 0));
            float v1 = __uint_as_float(__builtin_amdgcn_readlane(v_i, j + 1));
            float v2 = __uint_as_float(__builtin_amdgcn_readlane(v_i, j + 2));
            float v3 = __uint_as_float(__builtin_amdgcn_readlane(v_i, j + 3));
            acc += v0 * s0; acc += v1 * s1; acc += v2 * s2; acc += v3 * s3;
        }
        for (; j < cnt; ++j) {
            int c = __builtin_amdgcn_readlane(c_l, j);
            float v = __uint_as_float(__builtin_amdgcn_readlane(v_i, j));
            acc += v * bf2f(srch[(size_t)c * DIM + d]);
        }
    }
    return acc;
}

// ---------- SpMM layers 1&2: bf16 in, bf16 out ----------
__global__ void spmm_row_kernel(const int* __restrict__ row_ptr,
                                const int2* __restrict__ sorted,
                                const unsigned short* __restrict__ srch,
                                unsigned short* __restrict__ dsth) {
    int t = blockIdx.x * blockDim.x + threadIdx.x;
    int r = t >> 6;
    int d = t & 63;
    if (r >= N_NODES) return;
    float acc = row_accum(row_ptr[r], row_ptr[r + 1], d, sorted, srch);
    dsth[(size_t)r * DIM + d] = f2bf(acc);
}

// ---------- SpMM layer 3 fused with epilogue ----------
// out = 0.25*(emb_f32 + y1 + y2 + acc3), acc3 kept in f32 (never bf16-rounded)
__global__ void spmm_final_kernel(const int* __restrict__ row_ptr,
                                  const int2* __restrict__ sorted,
                                  const unsigned short* __restrict__ y2h,  // gather src
                                  const unsigned short* __restrict__ y1h,
                                  const float* __restrict__ user,
                                  const float* __restrict__ item,
                                  float* __restrict__ out) {
    int t = blockIdx.x * blockDim.x + threadIdx.x;
    int r = t >> 6;
    int d = t & 63;
    if (r >= N_NODES) return;
    float acc = row_accum(row_ptr[r], row_ptr[r + 1], d, sorted, y2h);
    size_t idx = (size_t)r * DIM + d;
    float base = (r < N_USERS) ? user[idx]
                               : item[idx - (size_t)N_USERS * DIM];
    out[idx] = 0.25f * (base + bf2f(y1h[idx]) + bf2f(y2h[idx]) + acc);
}

extern "C" void kernel_launch(void* const* d_in, const int* in_sizes, int n_in,
                              void* d_out, int out_size, void* d_ws, size_t ws_size,
                              hipStream_t stream) {
    const float* user = (const float*)d_in[0];
    const float* item = (const float*)d_in[1];
    const int*   rows = (const int*)d_in[2];
    const int*   cols = (const int*)d_in[3];
    const float* vals = (const float*)d_in[4];
    int nnz = in_sizes[2];

    float* out = (float*)d_out;

    // workspace layout (all offsets multiples of 16)
    char* p = (char*)d_ws;
    unsigned short* xh  = (unsigned short*)p; p += TOT_ELEMS * 2;    // 38.4 MB
    unsigned short* y1h = (unsigned short*)p; p += TOT_ELEMS * 2;    // 38.4 MB
    unsigned short* y2h = (unsigned short*)p; p += TOT_ELEMS * 2;    // 38.4 MB
    int2* binned = (int2*)p; p += (size_t)nnz * sizeof(int2);        // 51.2 MB
    int2* sorted = (int2*)p; p += (size_t)nnz * sizeof(int2);        // 51.2 MB
    int* row_ptr       = (int*)p; p += (size_t)(N_NODES + 1) * 4;
    int* bucket_count  = (int*)p; p += (size_t)NBUCKET * 4;
    int* bucket_base   = (int*)p; p += (size_t)(NBUCKET + 1) * 4;
    int* bucket_cursor = (int*)p; p += (size_t)NBUCKET * 4;

    const int BLK = 256;
    int grid_elem = (int)((TOT_F4 + BLK - 1) / BLK);                 // 18750
    int grid_binA = (nnz + EDGES_PER_BLOCK - 1) / EDGES_PER_BLOCK;   // 782
    int grid_rows = (N_NODES * 64 + BLK - 1) / BLK;                  // 75000

    init_kernel<<<grid_elem, BLK, 0, stream>>>(
        (const float4*)user, (const float4*)item, (ushort4*)xh);

    // bucket offsets (no per-row global histogram)
    zero_buckets_kernel<<<(NBUCKET + BLK - 1) / BLK, BLK, 0, stream>>>(bucket_count);
    bucket_hist_kernel<<<grid_binA, BLK, 0, stream>>>(rows, bucket_count, nnz);
    bucket_scan_kernel<<<1, 1024, 0, stream>>>(bucket_count, bucket_base, bucket_cursor, nnz);

    // two-pass binned sort into CSR order (binB also emits row_ptr)
    binA_kernel<<<grid_binA, BLK, 0, stream>>>(rows, cols, vals, bucket_cursor, binned, nnz);
    binB_kernel<<<NBUCKET, BLK, 0, stream>>>(bucket_base, binned, sorted, row_ptr, nnz);

    // 3 propagation layers (bf16 state); layer 3 fused with epilogue
    spmm_row_kernel<<<grid_rows, BLK, 0, stream>>>(row_ptr, sorted, xh,  y1h);
    spmm_row_kernel<<<grid_rows, BLK, 0, stream>>>(row_ptr, sorted, y1h, y2h);
    spmm_final_kernel<<<grid_rows, BLK, 0, stream>>>(row_ptr, sorted, y2h, y1h,
                                                     user, item, out);
}

// Round 3
// 887.771 us; speedup vs baseline: 1.0318x; 1.0318x over previous
//
#include <hip/hip_runtime.h>
#include <hip/hip_bf16.h>

#define N_USERS 100000
#define N_ITEMS 200000
#define N_NODES 300000
#define DIM 64

#define TOT_ELEMS ((size_t)N_NODES * DIM)          // 19,200,000 floats
#define TOT_F4    (TOT_ELEMS / 4)                  // 4,800,000
#define USER_F4   (((size_t)N_USERS * DIM) / 4)    // 1,600,000

#define BROWS 512
#define NBUCKET ((N_NODES + BROWS - 1) / BROWS)    // 586
#define EPT 32
#define EDGES_PER_BLOCK (EPT * 256)                // 8192

typedef float f4_native __attribute__((ext_vector_type(4)));

__device__ __forceinline__ float bf2f(unsigned short u) {
    return __uint_as_float((unsigned int)u << 16);
}
__device__ __forceinline__ unsigned short f2bf(float f) {
    __hip_bfloat16 h = __float2bfloat16(f);   // RNE
    return *reinterpret_cast<unsigned short*>(&h);
}
__device__ __forceinline__ float lo_bf(unsigned int u) {   // low ushort -> f32
    return __uint_as_float(u << 16);
}
__device__ __forceinline__ float hi_bf(unsigned int u) {   // high ushort -> f32
    return __uint_as_float(u & 0xFFFF0000u);
}

// ---------- init: xh = bf16(concat(user,item)) ----------
__global__ void init_kernel(const float* __restrict__ user,
                            const float* __restrict__ item,
                            ushort4* __restrict__ xh) {
    size_t i = (size_t)blockIdx.x * blockDim.x + threadIdx.x;
    if (i >= TOT_F4) return;
    f4_native v = (i < USER_F4)
        ? __builtin_nontemporal_load((const f4_native*)user + i)
        : __builtin_nontemporal_load((const f4_native*)item + (i - USER_F4));
    ushort4 h;
    h.x = f2bf(v.x); h.y = f2bf(v.y); h.z = f2bf(v.z); h.w = f2bf(v.w);
    xh[i] = h;   // cached: gather source of layer 1
}

// ---------- bucket-level histogram (586 counters, cache-resident) ----------
__global__ void zero_buckets_kernel(int* __restrict__ bucket_count) {
    int i = blockIdx.x * blockDim.x + threadIdx.x;
    if (i < NBUCKET) bucket_count[i] = 0;
}

__global__ void bucket_hist_kernel(const int* __restrict__ rows,
                                   int* __restrict__ bucket_count, int nnz) {
    __shared__ int h[NBUCKET];
    int t = threadIdx.x;
    size_t base = (size_t)blockIdx.x * EDGES_PER_BLOCK;
    for (int i = t; i < NBUCKET; i += 256) h[i] = 0;
    __syncthreads();
    #pragma unroll 4
    for (int k = 0; k < EPT; ++k) {
        size_t e = base + (size_t)k * 256 + t;
        if (e < (size_t)nnz) atomicAdd(&h[rows[e] >> 9], 1);
    }
    __syncthreads();
    for (int i = t; i < NBUCKET; i += 256) {
        int c = h[i];
        if (c) atomicAdd(&bucket_count[i], c);
    }
}

// exclusive scan of bucket counts -> bucket_base[0..NBUCKET], seed bucket_cursor
__global__ void bucket_scan_kernel(const int* __restrict__ bucket_count,
                                   int* __restrict__ bucket_base,
                                   int* __restrict__ bucket_cursor, int nnz) {
    __shared__ int s[1024];
    int t = threadIdx.x;
    int orig = (t < NBUCKET) ? bucket_count[t] : 0;
    s[t] = orig;
    __syncthreads();
    for (int off = 1; off < 1024; off <<= 1) {
        int v = (t >= off) ? s[t - off] : 0;
        __syncthreads();
        s[t] += v;
        __syncthreads();
    }
    if (t < NBUCKET) {
        int excl = s[t] - orig;
        bucket_base[t]   = excl;
        bucket_cursor[t] = excl;
    }
    if (t == 0) bucket_base[NBUCKET] = nnz;
}

// ---------- Pass A: bin edges into bucket ranges ----------
// payload: (.x = localrow<<19 | col, .y = val bits)
__global__ void binA_kernel(const int* __restrict__ rows,
                            const int* __restrict__ cols,
                            const float* __restrict__ vals,
                            int* __restrict__ bucket_cursor,
                            int2* __restrict__ binned,
                            int nnz) {
    __shared__ int h[NBUCKET];
    int t = threadIdx.x;
    size_t base = (size_t)blockIdx.x * EDGES_PER_BLOCK;
    for (int i = t; i < NBUCKET; i += 256) h[i] = 0;
    __syncthreads();
    #pragma unroll 4
    for (int k = 0; k < EPT; ++k) {
        size_t e = base + (size_t)k * 256 + t;
        if (e < (size_t)nnz) atomicAdd(&h[rows[e] >> 9], 1);
    }
    __syncthreads();
    for (int i = t; i < NBUCKET; i += 256) {
        int c = h[i];
        h[i] = (c > 0) ? atomicAdd(&bucket_cursor[i], c) : 0;
    }
    __syncthreads();
    #pragma unroll 4
    for (int k = 0; k < EPT; ++k) {
        size_t e = base + (size_t)k * 256 + t;
        if (e < (size_t)nnz) {
            int r = rows[e];
            int pos = atomicAdd(&h[r >> 9], 1);
            int c   = __builtin_nontemporal_load(cols + e);
            float v = __builtin_nontemporal_load(vals + e);
            binned[pos] = make_int2(((r & (BROWS - 1)) << 19) | c,
                                    __float_as_int(v));
        }
    }
}

// ---------- Pass B: per-row histogram + scan -> row_ptr, then permute ----------
__global__ void binB_kernel(const int* __restrict__ bucket_base,
                            const int2* __restrict__ binned,
                            int2* __restrict__ sorted,
                            int* __restrict__ row_ptr,
                            int nnz) {
    __shared__ int cnt[BROWS];
    __shared__ int cur[BROWS];
    __shared__ int s[256];
    int b = blockIdx.x, t = threadIdx.x;
    int beg = bucket_base[b];
    int end = bucket_base[b + 1];
    int row0 = b * BROWS;
    for (int i = t; i < BROWS; i += 256) cnt[i] = 0;
    __syncthreads();
    // per-row histogram of this bucket's edges
    for (int idx = beg + t; idx < end; idx += 256) {
        int lr = ((unsigned)binned[idx].x) >> 19;
        atomicAdd(&cnt[lr], 1);
    }
    __syncthreads();
    // exclusive scan of 512 counts (2 per thread)
    int c0 = cnt[2 * t], c1 = cnt[2 * t + 1];
    int local = c0 + c1;
    s[t] = local;
    __syncthreads();
    for (int off = 1; off < 256; off <<= 1) {
        int v = (t >= off) ? s[t - off] : 0;
        __syncthreads();
        s[t] += v;
        __syncthreads();
    }
    int excl = beg + s[t] - local;
    int r0 = row0 + 2 * t;
    if (r0 < N_NODES)     row_ptr[r0]     = excl;
    if (r0 + 1 < N_NODES) row_ptr[r0 + 1] = excl + c0;
    cur[2 * t]     = excl;
    cur[2 * t + 1] = excl + c0;
    __syncthreads();
    // permute to exact CSR order (sorted stays cached: re-read by 3 layers)
    for (int idx = beg + t; idx < end; idx += 256) {
        int2 e = binned[idx];
        int lr  = ((unsigned)e.x) >> 19;
        int col = e.x & 0x7FFFF;
        int pos = atomicAdd(&cur[lr], 1);
        sorted[pos] = make_int2(col, e.y);
    }
    if (b == 0 && t == 0) row_ptr[N_NODES] = nnz;
}

// ---------- row accumulate: one wave per row ----------
// Lane l: h = l>>5 selects even/odd edge of a pair, q = l&31 selects the
// dword (2 bf16 dims) within the row. Per edge-pair: 2 ds_bpermute (idle LDS
// pipe) broadcast col/val, 1 dword gather, 2 unpack, 2 fma.
// acc0/acc1 hold dims {2q, 2q+1}; cross-half sum folded once per row.
__device__ __forceinline__ void row_accum2(int beg, int end, int l,
                                           const int2* __restrict__ sorted,
                                           const unsigned short* __restrict__ srch,
                                           float& r0, float& r1) {
    const int h4 = (l >> 5) << 2;      // bpermute byte index base (h*4)
    const unsigned int q = (unsigned)(l & 31);
    const unsigned int* __restrict__ srcd = (const unsigned int*)srch;
    float acc0 = 0.f, acc1 = 0.f;

    for (int base = beg; base < end; base += 64) {
        int rem = end - base;
        int cnt = rem > 64 ? 64 : rem;
        int c_l = 0, v_l = 0;
        if (base + l < end) {
            unsigned long long e = __builtin_nontemporal_load(
                (const unsigned long long*)sorted + base + l);
            c_l = (int)(unsigned int)(e & 0xFFFFFFFFull);
            v_l = (int)(unsigned int)(e >> 32);
        }
        int npairs = (cnt + 1) >> 1;
        int p = 0;
        for (; p + 8 <= npairs; p += 8) {
            int i0 = h4 + (p << 3);
            int c0 = __builtin_amdgcn_ds_bpermute(i0 +  0, c_l);
            int c1 = __builtin_amdgcn_ds_bpermute(i0 +  8, c_l);
            int c2 = __builtin_amdgcn_ds_bpermute(i0 + 16, c_l);
            int c3 = __builtin_amdgcn_ds_bpermute(i0 + 24, c_l);
            int c4 = __builtin_amdgcn_ds_bpermute(i0 + 32, c_l);
            int c5 = __builtin_amdgcn_ds_bpermute(i0 + 40, c_l);
            int c6 = __builtin_amdgcn_ds_bpermute(i0 + 48, c_l);
            int c7 = __builtin_amdgcn_ds_bpermute(i0 + 56, c_l);
            unsigned int u0 = srcd[((unsigned int)c0 << 5) | q];
            unsigned int u1 = srcd[((unsigned int)c1 << 5) | q];
            unsigned int u2 = srcd[((unsigned int)c2 << 5) | q];
            unsigned int u3 = srcd[((unsigned int)c3 << 5) | q];
            unsigned int u4 = srcd[((unsigned int)c4 << 5) | q];
            unsigned int u5 = srcd[((unsigned int)c5 << 5) | q];
            unsigned int u6 = srcd[((unsigned int)c6 << 5) | q];
            unsigned int u7 = srcd[((unsigned int)c7 << 5) | q];
            float v0 = __int_as_float(__builtin_amdgcn_ds_bpermute(i0 +  0, v_l));
            float v1 = __int_as_float(__builtin_amdgcn_ds_bpermute(i0 +  8, v_l));
            float v2 = __int_as_float(__builtin_amdgcn_ds_bpermute(i0 + 16, v_l));
            float v3 = __int_as_float(__builtin_amdgcn_ds_bpermute(i0 + 24, v_l));
            float v4 = __int_as_float(__builtin_amdgcn_ds_bpermute(i0 + 32, v_l));
            float v5 = __int_as_float(__builtin_amdgcn_ds_bpermute(i0 + 40, v_l));
            float v6 = __int_as_float(__builtin_amdgcn_ds_bpermute(i0 + 48, v_l));
            float v7 = __int_as_float(__builtin_amdgcn_ds_bpermute(i0 + 56, v_l));
            acc0 = fmaf(v0, lo_bf(u0), acc0); acc1 = fmaf(v0, hi_bf(u0), acc1);
            acc0 = fmaf(v1, lo_bf(u1), acc0); acc1 = fmaf(v1, hi_bf(u1), acc1);
            acc0 = fmaf(v2, lo_bf(u2), acc0); acc1 = fmaf(v2, hi_bf(u2), acc1);
            acc0 = fmaf(v3, lo_bf(u3), acc0); acc1 = fmaf(v3, hi_bf(u3), acc1);
            acc0 = fmaf(v4, lo_bf(u4), acc0); acc1 = fmaf(v4, hi_bf(u4), acc1);
            acc0 = fmaf(v5, lo_bf(u5), acc0); acc1 = fmaf(v5, hi_bf(u5), acc1);
            acc0 = fmaf(v6, lo_bf(u6), acc0); acc1 = fmaf(v6, hi_bf(u6), acc1);
            acc0 = fmaf(v7, lo_bf(u7), acc0); acc1 = fmaf(v7, hi_bf(u7), acc1);
        }
        for (; p + 4 <= npairs; p += 4) {
            int i0 = h4 + (p << 3);
            int c0 = __builtin_amdgcn_ds_bpermute(i0 +  0, c_l);
            int c1 = __builtin_amdgcn_ds_bpermute(i0 +  8, c_l);
            int c2 = __builtin_amdgcn_ds_bpermute(i0 + 16, c_l);
            int c3 = __builtin_amdgcn_ds_bpermute(i0 + 24, c_l);
            unsigned int u0 = srcd[((unsigned int)c0 << 5) | q];
            unsigned int u1 = srcd[((unsigned int)c1 << 5) | q];
            unsigned int u2 = srcd[((unsigned int)c2 << 5) | q];
            unsigned int u3 = srcd[((unsigned int)c3 << 5) | q];
            float v0 = __int_as_float(__builtin_amdgcn_ds_bpermute(i0 +  0, v_l));
            float v1 = __int_as_float(__builtin_amdgcn_ds_bpermute(i0 +  8, v_l));
            float v2 = __int_as_float(__builtin_amdgcn_ds_bpermute(i0 + 16, v_l));
            float v3 = __int_as_float(__builtin_amdgcn_ds_bpermute(i0 + 24, v_l));
            acc0 = fmaf(v0, lo_bf(u0), acc0); acc1 = fmaf(v0, hi_bf(u0), acc1);
            acc0 = fmaf(v1, lo_bf(u1), acc0); acc1 = fmaf(v1, hi_bf(u1), acc1);
            acc0 = fmaf(v2, lo_bf(u2), acc0); acc1 = fmaf(v2, hi_bf(u2), acc1);
            acc0 = fmaf(v3, lo_bf(u3), acc0); acc1 = fmaf(v3, hi_bf(u3), acc1);
        }
        for (; p < npairs; ++p) {
            int i0 = h4 + (p << 3);
            int c0 = __builtin_amdgcn_ds_bpermute(i0, c_l);
            unsigned int u0 = srcd[((unsigned int)c0 << 5) | q];
            float v0 = __int_as_float(__builtin_amdgcn_ds_bpermute(i0, v_l));
            acc0 = fmaf(v0, lo_bf(u0), acc0);
            acc1 = fmaf(v0, hi_bf(u0), acc1);
        }
    }
    // fold even/odd edge halves: dim 2q = acc0(lane q) + acc0(lane q+32)
    r0 = acc0 + __shfl_xor(acc0, 32);
    r1 = acc1 + __shfl_xor(acc1, 32);
}

// ---------- SpMM layers 1&2: bf16 in, bf16 out (packed dword store) ----------
__global__ void spmm_row_kernel(const int* __restrict__ row_ptr,
                                const int2* __restrict__ sorted,
                                const unsigned short* __restrict__ srch,
                                unsigned short* __restrict__ dsth) {
    int t = blockIdx.x * blockDim.x + threadIdx.x;
    int r = t >> 6;
    int l = t & 63;
    if (r >= N_NODES) return;
    float r0, r1;
    row_accum2(row_ptr[r], row_ptr[r + 1], l, sorted, srch, r0, r1);
    if (l < 32) {
        unsigned int pack = (unsigned int)f2bf(r0) | ((unsigned int)f2bf(r1) << 16);
        ((unsigned int*)dsth)[(size_t)r * 32 + l] = pack;   // cached: next gather src
    }
}

// ---------- SpMM layer 3 fused with epilogue ----------
// out = 0.25*(emb_f32 + y1 + y2 + acc3); streams are nontemporal so L3 keeps
// the gather sources (y2h) + sorted resident.
__global__ void spmm_final_kernel(const int* __restrict__ row_ptr,
                                  const int2* __restrict__ sorted,
                                  const unsigned short* __restrict__ y2h,  // gather src
                                  const unsigned short* __restrict__ y1h,
                                  const float* __restrict__ user,
                                  const float* __restrict__ item,
                                  float* __restrict__ out) {
    int t = blockIdx.x * blockDim.x + threadIdx.x;
    int r = t >> 6;
    int l = t & 63;
    if (r >= N_NODES) return;
    float r0, r1;
    row_accum2(row_ptr[r], row_ptr[r + 1], l, sorted, y2h, r0, r1);
    if (l < 32) {
        size_t didx = (size_t)r * 32 + l;                 // dword units
        unsigned int y1d = __builtin_nontemporal_load((const unsigned int*)y1h + didx);
        unsigned int y2d = __builtin_nontemporal_load((const unsigned int*)y2h + didx);
        const float* bp = (r < N_USERS) ? (user + 2 * didx)
                                        : (item + 2 * (didx - (size_t)N_USERS * 32));
        float b0 = __builtin_nontemporal_load(bp + 0);
        float b1 = __builtin_nontemporal_load(bp + 1);
        float o0 = 0.25f * (b0 + lo_bf(y1d) + lo_bf(y2d) + r0);
        float o1 = 0.25f * (b1 + hi_bf(y1d) + hi_bf(y2d) + r1);
        __builtin_nontemporal_store(o0, out + 2 * didx + 0);
        __builtin_nontemporal_store(o1, out + 2 * didx + 1);
    }
}

extern "C" void kernel_launch(void* const* d_in, const int* in_sizes, int n_in,
                              void* d_out, int out_size, void* d_ws, size_t ws_size,
                              hipStream_t stream) {
    const float* user = (const float*)d_in[0];
    const float* item = (const float*)d_in[1];
    const int*   rows = (const int*)d_in[2];
    const int*   cols = (const int*)d_in[3];
    const float* vals = (const float*)d_in[4];
    int nnz = in_sizes[2];

    float* out = (float*)d_out;

    // workspace layout (all offsets multiples of 16)
    char* p = (char*)d_ws;
    unsigned short* xh  = (unsigned short*)p; p += TOT_ELEMS * 2;    // 38.4 MB
    unsigned short* y1h = (unsigned short*)p; p += TOT_ELEMS * 2;    // 38.4 MB
    unsigned short* y2h = (unsigned short*)p; p += TOT_ELEMS * 2;    // 38.4 MB
    int2* binned = (int2*)p; p += (size_t)nnz * sizeof(int2);        // 51.2 MB
    int2* sorted = (int2*)p; p += (size_t)nnz * sizeof(int2);        // 51.2 MB
    int* row_ptr       = (int*)p; p += (size_t)(N_NODES + 1) * 4;
    int* bucket_count  = (int*)p; p += (size_t)NBUCKET * 4;
    int* bucket_base   = (int*)p; p += (size_t)(NBUCKET + 1) * 4;
    int* bucket_cursor = (int*)p; p += (size_t)NBUCKET * 4;

    const int BLK = 256;
    int grid_elem = (int)((TOT_F4 + BLK - 1) / BLK);                 // 18750
    int grid_binA = (nnz + EDGES_PER_BLOCK - 1) / EDGES_PER_BLOCK;   // 782
    int grid_rows = (N_NODES * 64 + BLK - 1) / BLK;                  // 75000

    init_kernel<<<grid_elem, BLK, 0, stream>>>(user, item, (ushort4*)xh);

    // bucket offsets (no per-row global histogram)
    zero_buckets_kernel<<<(NBUCKET + BLK - 1) / BLK, BLK, 0, stream>>>(bucket_count);
    bucket_hist_kernel<<<grid_binA, BLK, 0, stream>>>(rows, bucket_count, nnz);
    bucket_scan_kernel<<<1, 1024, 0, stream>>>(bucket_count, bucket_base, bucket_cursor, nnz);

    // two-pass binned sort into CSR order (binB also emits row_ptr)
    binA_kernel<<<grid_binA, BLK, 0, stream>>>(rows, cols, vals, bucket_cursor, binned, nnz);
    binB_kernel<<<NBUCKET, BLK, 0, stream>>>(bucket_base, binned, sorted, row_ptr, nnz);

    // 3 propagation layers (bf16 state); layer 3 fused with epilogue
    spmm_row_kernel<<<grid_rows, BLK, 0, stream>>>(row_ptr, sorted, xh,  y1h);
    spmm_row_kernel<<<grid_rows, BLK, 0, stream>>>(row_ptr, sorted, y1h, y2h);
    spmm_final_kernel<<<grid_rows, BLK, 0, stream>>>(row_ptr, sorted, y2h, y1h,
                                                     user, item, out);
}

// Round 4
// 813.478 us; speedup vs baseline: 1.1260x; 1.0913x over previous
//
#include <hip/hip_runtime.h>
#include <hip/hip_bf16.h>

#define N_USERS 100000
#define N_ITEMS 200000
#define N_NODES 300000
#define DIM 64

#define TOT_ELEMS ((size_t)N_NODES * DIM)          // 19,200,000 floats
#define TOT_F4    (TOT_ELEMS / 4)                  // 4,800,000
#define USER_F4   (((size_t)N_USERS * DIM) / 4)    // 1,600,000

#define BROWS 512
#define NBUCKET ((N_NODES + BROWS - 1) / BROWS)    // 586
#define EPT 32
#define EDGES_PER_BLOCK (EPT * 256)                // 8192

typedef float f4_native __attribute__((ext_vector_type(4)));

__device__ __forceinline__ float bf2f(unsigned short u) {
    return __uint_as_float((unsigned int)u << 16);
}
__device__ __forceinline__ unsigned short f2bf(float f) {
    __hip_bfloat16 h = __float2bfloat16(f);   // RNE
    return *reinterpret_cast<unsigned short*>(&h);
}
__device__ __forceinline__ float lo_bf(unsigned int u) {   // low ushort -> f32
    return __uint_as_float(u << 16);
}
__device__ __forceinline__ float hi_bf(unsigned int u) {   // high ushort -> f32
    return __uint_as_float(u & 0xFFFF0000u);
}

// ---------- init: xh = bf16(concat(user,item)) ----------
__global__ void init_kernel(const float* __restrict__ user,
                            const float* __restrict__ item,
                            ushort4* __restrict__ xh) {
    size_t i = (size_t)blockIdx.x * blockDim.x + threadIdx.x;
    if (i >= TOT_F4) return;
    f4_native v = (i < USER_F4)
        ? __builtin_nontemporal_load((const f4_native*)user + i)
        : __builtin_nontemporal_load((const f4_native*)item + (i - USER_F4));
    ushort4 h;
    h.x = f2bf(v.x); h.y = f2bf(v.y); h.z = f2bf(v.z); h.w = f2bf(v.w);
    xh[i] = h;   // cached: gather source of layer 1
}

// ---------- bucket-level histogram (586 counters, cache-resident) ----------
__global__ void zero_buckets_kernel(int* __restrict__ bucket_count) {
    int i = blockIdx.x * blockDim.x + threadIdx.x;
    if (i < NBUCKET) bucket_count[i] = 0;
}

__global__ void bucket_hist_kernel(const int* __restrict__ rows,
                                   int* __restrict__ bucket_count, int nnz) {
    __shared__ int h[NBUCKET];
    int t = threadIdx.x;
    size_t base = (size_t)blockIdx.x * EDGES_PER_BLOCK;
    for (int i = t; i < NBUCKET; i += 256) h[i] = 0;
    __syncthreads();
    #pragma unroll 4
    for (int k = 0; k < EPT; ++k) {
        size_t e = base + (size_t)k * 256 + t;
        if (e < (size_t)nnz) atomicAdd(&h[rows[e] >> 9], 1);
    }
    __syncthreads();
    for (int i = t; i < NBUCKET; i += 256) {
        int c = h[i];
        if (c) atomicAdd(&bucket_count[i], c);
    }
}

// exclusive scan of bucket counts -> bucket_base[0..NBUCKET], seed bucket_cursor
__global__ void bucket_scan_kernel(const int* __restrict__ bucket_count,
                                   int* __restrict__ bucket_base,
                                   int* __restrict__ bucket_cursor, int nnz) {
    __shared__ int s[1024];
    int t = threadIdx.x;
    int orig = (t < NBUCKET) ? bucket_count[t] : 0;
    s[t] = orig;
    __syncthreads();
    for (int off = 1; off < 1024; off <<= 1) {
        int v = (t >= off) ? s[t - off] : 0;
        __syncthreads();
        s[t] += v;
        __syncthreads();
    }
    if (t < NBUCKET) {
        int excl = s[t] - orig;
        bucket_base[t]   = excl;
        bucket_cursor[t] = excl;
    }
    if (t == 0) bucket_base[NBUCKET] = nnz;
}

// ---------- Pass A: LDS counting-sort per block, then coalesced write-out ----
// Each block sorts its 8192 edges by bucket in LDS; write-out is slot-major so
// consecutive lanes hit consecutive global addresses (bursts of ~14 edges per
// bucket chunk) instead of 64 divergent 8B stores per wave.
// payload: (.x = localrow<<19 | col, .y = val bits)
__global__ void binA_kernel(const int* __restrict__ rows,
                            const int* __restrict__ cols,
                            const float* __restrict__ vals,
                            int* __restrict__ bucket_cursor,
                            int2* __restrict__ binned,
                            int nnz) {
    __shared__ int  h[NBUCKET];       // per-bucket counts
    __shared__ int  lstart[NBUCKET];  // local exclusive starts
    __shared__ int  lcur[NBUCKET];    // staging cursors
    __shared__ int  gbase[NBUCKET];   // reserved global bases
    __shared__ int  s[256];           // scan temp
    __shared__ int2 ledge[EDGES_PER_BLOCK];   // 64 KB staging

    int t = threadIdx.x;
    size_t base = (size_t)blockIdx.x * EDGES_PER_BLOCK;
    int nvalid = (int)(((size_t)nnz - base < (size_t)EDGES_PER_BLOCK)
                       ? ((size_t)nnz - base) : (size_t)EDGES_PER_BLOCK);

    for (int i = t; i < NBUCKET; i += 256) h[i] = 0;
    __syncthreads();

    // phase 1: local bucket histogram
    #pragma unroll 4
    for (int k = 0; k < EPT; ++k) {
        int e = k * 256 + t;
        if (e < nvalid) atomicAdd(&h[rows[base + e] >> 9], 1);
    }
    __syncthreads();

    // phase 2: exclusive scan of 586 counts (3 per thread + 256-wide HS scan)
    int i0 = 3 * t, i1 = 3 * t + 1, i2 = 3 * t + 2;
    int c0 = (i0 < NBUCKET) ? h[i0] : 0;
    int c1 = (i1 < NBUCKET) ? h[i1] : 0;
    int c2 = (i2 < NBUCKET) ? h[i2] : 0;
    int g = c0 + c1 + c2;
    s[t] = g;
    __syncthreads();
    for (int off = 1; off < 256; off <<= 1) {
        int v = (t >= off) ? s[t - off] : 0;
        __syncthreads();
        s[t] += v;
        __syncthreads();
    }
    int excl = s[t] - g;
    if (i0 < NBUCKET) { lstart[i0] = excl;           lcur[i0] = excl; }
    if (i1 < NBUCKET) { lstart[i1] = excl + c0;      lcur[i1] = excl + c0; }
    if (i2 < NBUCKET) { lstart[i2] = excl + c0 + c1; lcur[i2] = excl + c0 + c1; }

    // phase 3: reserve global space per bucket (no barrier needed vs scan:
    // reads h only, which is stable since the histogram barrier)
    for (int i = t; i < NBUCKET; i += 256) {
        int c = h[i];
        gbase[i] = c ? atomicAdd(&bucket_cursor[i], c) : 0;
    }
    __syncthreads();   // covers lstart/lcur/gbase before use

    // phase 4: stage edges into LDS, sorted by bucket
    #pragma unroll 4
    for (int k = 0; k < EPT; ++k) {
        int e = k * 256 + t;
        if (e < nvalid) {
            size_t ge = base + e;
            int r = rows[ge];
            int c = __builtin_nontemporal_load(cols + ge);
            float v = __builtin_nontemporal_load(vals + ge);
            int slot = atomicAdd(&lcur[r >> 9], 1);
            ledge[slot] = make_int2(((r & (BROWS - 1)) << 19) | c,
                                    __float_as_int(v));
        }
    }
    __syncthreads();

    // phase 5: slot-major coalesced write-out; bucket via binary search on
    // lstart (largest b with lstart[b] <= slot; empty buckets resolve right)
    for (int slot = t; slot < nvalid; slot += 256) {
        int lo = 0, hi = NBUCKET;
        while (hi - lo > 1) {
            int mid = (lo + hi) >> 1;
            if (lstart[mid] <= slot) lo = mid; else hi = mid;
        }
        binned[gbase[lo] + (slot - lstart[lo])] = ledge[slot];
    }
}

// ---------- Pass B: per-row histogram + scan -> row_ptr, then permute ----------
__global__ void binB_kernel(const int* __restrict__ bucket_base,
                            const int2* __restrict__ binned,
                            int2* __restrict__ sorted,
                            int* __restrict__ row_ptr,
                            int nnz) {
    __shared__ int cnt[BROWS];
    __shared__ int cur[BROWS];
    __shared__ int s[256];
    int b = blockIdx.x, t = threadIdx.x;
    int beg = bucket_base[b];
    int end = bucket_base[b + 1];
    int row0 = b * BROWS;
    for (int i = t; i < BROWS; i += 256) cnt[i] = 0;
    __syncthreads();
    // per-row histogram of this bucket's edges
    for (int idx = beg + t; idx < end; idx += 256) {
        int lr = ((unsigned)binned[idx].x) >> 19;
        atomicAdd(&cnt[lr], 1);
    }
    __syncthreads();
    // exclusive scan of 512 counts (2 per thread)
    int c0 = cnt[2 * t], c1 = cnt[2 * t + 1];
    int local = c0 + c1;
    s[t] = local;
    __syncthreads();
    for (int off = 1; off < 256; off <<= 1) {
        int v = (t >= off) ? s[t - off] : 0;
        __syncthreads();
        s[t] += v;
        __syncthreads();
    }
    int excl = beg + s[t] - local;
    int r0 = row0 + 2 * t;
    if (r0 < N_NODES)     row_ptr[r0]     = excl;
    if (r0 + 1 < N_NODES) row_ptr[r0 + 1] = excl + c0;
    cur[2 * t]     = excl;
    cur[2 * t + 1] = excl + c0;
    __syncthreads();
    // permute to exact CSR order (sorted stays cached: re-read by 3 layers)
    for (int idx = beg + t; idx < end; idx += 256) {
        int2 e = binned[idx];
        int lr  = ((unsigned)e.x) >> 19;
        int col = e.x & 0x7FFFF;
        int pos = atomicAdd(&cur[lr], 1);
        sorted[pos] = make_int2(col, e.y);
    }
    if (b == 0 && t == 0) row_ptr[N_NODES] = nnz;
}

// ---------- row accumulate: one wave per row ----------
// Lane l: h = l>>5 selects even/odd edge of a pair, q = l&31 selects the
// dword (2 bf16 dims) within the row. Per edge-pair: 2 ds_bpermute (idle LDS
// pipe) broadcast col/val, 1 dword gather, 2 unpack, 2 fma.
// acc0/acc1 hold dims {2q, 2q+1}; cross-half sum folded once per row.
__device__ __forceinline__ void row_accum2(int beg, int end, int l,
                                           const int2* __restrict__ sorted,
                                           const unsigned short* __restrict__ srch,
                                           float& r0, float& r1) {
    const int h4 = (l >> 5) << 2;      // bpermute byte index base (h*4)
    const unsigned int q = (unsigned)(l & 31);
    const unsigned int* __restrict__ srcd = (const unsigned int*)srch;
    float acc0 = 0.f, acc1 = 0.f;

    for (int base = beg; base < end; base += 64) {
        int rem = end - base;
        int cnt = rem > 64 ? 64 : rem;
        int c_l = 0, v_l = 0;
        if (base + l < end) {
            unsigned long long e = __builtin_nontemporal_load(
                (const unsigned long long*)sorted + base + l);
            c_l = (int)(unsigned int)(e & 0xFFFFFFFFull);
            v_l = (int)(unsigned int)(e >> 32);
        }
        int npairs = (cnt + 1) >> 1;
        int p = 0;
        for (; p + 8 <= npairs; p += 8) {
            int i0 = h4 + (p << 3);
            int c0 = __builtin_amdgcn_ds_bpermute(i0 +  0, c_l);
            int c1 = __builtin_amdgcn_ds_bpermute(i0 +  8, c_l);
            int c2 = __builtin_amdgcn_ds_bpermute(i0 + 16, c_l);
            int c3 = __builtin_amdgcn_ds_bpermute(i0 + 24, c_l);
            int c4 = __builtin_amdgcn_ds_bpermute(i0 + 32, c_l);
            int c5 = __builtin_amdgcn_ds_bpermute(i0 + 40, c_l);
            int c6 = __builtin_amdgcn_ds_bpermute(i0 + 48, c_l);
            int c7 = __builtin_amdgcn_ds_bpermute(i0 + 56, c_l);
            unsigned int u0 = srcd[((unsigned int)c0 << 5) | q];
            unsigned int u1 = srcd[((unsigned int)c1 << 5) | q];
            unsigned int u2 = srcd[((unsigned int)c2 << 5) | q];
            unsigned int u3 = srcd[((unsigned int)c3 << 5) | q];
            unsigned int u4 = srcd[((unsigned int)c4 << 5) | q];
            unsigned int u5 = srcd[((unsigned int)c5 << 5) | q];
            unsigned int u6 = srcd[((unsigned int)c6 << 5) | q];
            unsigned int u7 = srcd[((unsigned int)c7 << 5) | q];
            float v0 = __int_as_float(__builtin_amdgcn_ds_bpermute(i0 +  0, v_l));
            float v1 = __int_as_float(__builtin_amdgcn_ds_bpermute(i0 +  8, v_l));
            float v2 = __int_as_float(__builtin_amdgcn_ds_bpermute(i0 + 16, v_l));
            float v3 = __int_as_float(__builtin_amdgcn_ds_bpermute(i0 + 24, v_l));
            float v4 = __int_as_float(__builtin_amdgcn_ds_bpermute(i0 + 32, v_l));
            float v5 = __int_as_float(__builtin_amdgcn_ds_bpermute(i0 + 40, v_l));
            float v6 = __int_as_float(__builtin_amdgcn_ds_bpermute(i0 + 48, v_l));
            float v7 = __int_as_float(__builtin_amdgcn_ds_bpermute(i0 + 56, v_l));
            acc0 = fmaf(v0, lo_bf(u0), acc0); acc1 = fmaf(v0, hi_bf(u0), acc1);
            acc0 = fmaf(v1, lo_bf(u1), acc0); acc1 = fmaf(v1, hi_bf(u1), acc1);
            acc0 = fmaf(v2, lo_bf(u2), acc0); acc1 = fmaf(v2, hi_bf(u2), acc1);
            acc0 = fmaf(v3, lo_bf(u3), acc0); acc1 = fmaf(v3, hi_bf(u3), acc1);
            acc0 = fmaf(v4, lo_bf(u4), acc0); acc1 = fmaf(v4, hi_bf(u4), acc1);
            acc0 = fmaf(v5, lo_bf(u5), acc0); acc1 = fmaf(v5, hi_bf(u5), acc1);
            acc0 = fmaf(v6, lo_bf(u6), acc0); acc1 = fmaf(v6, hi_bf(u6), acc1);
            acc0 = fmaf(v7, lo_bf(u7), acc0); acc1 = fmaf(v7, hi_bf(u7), acc1);
        }
        for (; p + 4 <= npairs; p += 4) {
            int i0 = h4 + (p << 3);
            int c0 = __builtin_amdgcn_ds_bpermute(i0 +  0, c_l);
            int c1 = __builtin_amdgcn_ds_bpermute(i0 +  8, c_l);
            int c2 = __builtin_amdgcn_ds_bpermute(i0 + 16, c_l);
            int c3 = __builtin_amdgcn_ds_bpermute(i0 + 24, c_l);
            unsigned int u0 = srcd[((unsigned int)c0 << 5) | q];
            unsigned int u1 = srcd[((unsigned int)c1 << 5) | q];
            unsigned int u2 = srcd[((unsigned int)c2 << 5) | q];
            unsigned int u3 = srcd[((unsigned int)c3 << 5) | q];
            float v0 = __int_as_float(__builtin_amdgcn_ds_bpermute(i0 +  0, v_l));
            float v1 = __int_as_float(__builtin_amdgcn_ds_bpermute(i0 +  8, v_l));
            float v2 = __int_as_float(__builtin_amdgcn_ds_bpermute(i0 + 16, v_l));
            float v3 = __int_as_float(__builtin_amdgcn_ds_bpermute(i0 + 24, v_l));
            acc0 = fmaf(v0, lo_bf(u0), acc0); acc1 = fmaf(v0, hi_bf(u0), acc1);
            acc0 = fmaf(v1, lo_bf(u1), acc0); acc1 = fmaf(v1, hi_bf(u1), acc1);
            acc0 = fmaf(v2, lo_bf(u2), acc0); acc1 = fmaf(v2, hi_bf(u2), acc1);
            acc0 = fmaf(v3, lo_bf(u3), acc0); acc1 = fmaf(v3, hi_bf(u3), acc1);
        }
        for (; p < npairs; ++p) {
            int i0 = h4 + (p << 3);
            int c0 = __builtin_amdgcn_ds_bpermute(i0, c_l);
            unsigned int u0 = srcd[((unsigned int)c0 << 5) | q];
            float v0 = __int_as_float(__builtin_amdgcn_ds_bpermute(i0, v_l));
            acc0 = fmaf(v0, lo_bf(u0), acc0);
            acc1 = fmaf(v0, hi_bf(u0), acc1);
        }
    }
    // fold even/odd edge halves: dim 2q = acc0(lane q) + acc0(lane q+32)
    r0 = acc0 + __shfl_xor(acc0, 32);
    r1 = acc1 + __shfl_xor(acc1, 32);
}

// ---------- SpMM layers 1&2: bf16 in, bf16 out (packed dword store) ----------
__global__ void spmm_row_kernel(const int* __restrict__ row_ptr,
                                const int2* __restrict__ sorted,
                                const unsigned short* __restrict__ srch,
                                unsigned short* __restrict__ dsth) {
    int t = blockIdx.x * blockDim.x + threadIdx.x;
    int r = t >> 6;
    int l = t & 63;
    if (r >= N_NODES) return;
    float r0, r1;
    row_accum2(row_ptr[r], row_ptr[r + 1], l, sorted, srch, r0, r1);
    if (l < 32) {
        unsigned int pack = (unsigned int)f2bf(r0) | ((unsigned int)f2bf(r1) << 16);
        ((unsigned int*)dsth)[(size_t)r * 32 + l] = pack;   // cached: next gather src
    }
}

// ---------- SpMM layer 3 fused with epilogue ----------
// out = 0.25*(emb_f32 + y1 + y2 + acc3); streams are nontemporal so L3 keeps
// the gather sources (y2h) + sorted resident.
__global__ void spmm_final_kernel(const int* __restrict__ row_ptr,
                                  const int2* __restrict__ sorted,
                                  const unsigned short* __restrict__ y2h,  // gather src
                                  const unsigned short* __restrict__ y1h,
                                  const float* __restrict__ user,
                                  const float* __restrict__ item,
                                  float* __restrict__ out) {
    int t = blockIdx.x * blockDim.x + threadIdx.x;
    int r = t >> 6;
    int l = t & 63;
    if (r >= N_NODES) return;
    float r0, r1;
    row_accum2(row_ptr[r], row_ptr[r + 1], l, sorted, y2h, r0, r1);
    if (l < 32) {
        size_t didx = (size_t)r * 32 + l;                 // dword units
        unsigned int y1d = __builtin_nontemporal_load((const unsigned int*)y1h + didx);
        unsigned int y2d = __builtin_nontemporal_load((const unsigned int*)y2h + didx);
        const float* bp = (r < N_USERS) ? (user + 2 * didx)
                                        : (item + 2 * (didx - (size_t)N_USERS * 32));
        float b0 = __builtin_nontemporal_load(bp + 0);
        float b1 = __builtin_nontemporal_load(bp + 1);
        float o0 = 0.25f * (b0 + lo_bf(y1d) + lo_bf(y2d) + r0);
        float o1 = 0.25f * (b1 + hi_bf(y1d) + hi_bf(y2d) + r1);
        __builtin_nontemporal_store(o0, out + 2 * didx + 0);
        __builtin_nontemporal_store(o1, out + 2 * didx + 1);
    }
}

extern "C" void kernel_launch(void* const* d_in, const int* in_sizes, int n_in,
                              void* d_out, int out_size, void* d_ws, size_t ws_size,
                              hipStream_t stream) {
    const float* user = (const float*)d_in[0];
    const float* item = (const float*)d_in[1];
    const int*   rows = (const int*)d_in[2];
    const int*   cols = (const int*)d_in[3];
    const float* vals = (const float*)d_in[4];
    int nnz = in_sizes[2];

    float* out = (float*)d_out;

    // workspace layout (all offsets multiples of 16)
    char* p = (char*)d_ws;
    unsigned short* xh  = (unsigned short*)p; p += TOT_ELEMS * 2;    // 38.4 MB
    unsigned short* y1h = (unsigned short*)p; p += TOT_ELEMS * 2;    // 38.4 MB
    unsigned short* y2h = (unsigned short*)p; p += TOT_ELEMS * 2;    // 38.4 MB
    int2* binned = (int2*)p; p += (size_t)nnz * sizeof(int2);        // 51.2 MB
    int2* sorted = (int2*)p; p += (size_t)nnz * sizeof(int2);        // 51.2 MB
    int* row_ptr       = (int*)p; p += (size_t)(N_NODES + 1) * 4;
    int* bucket_count  = (int*)p; p += (size_t)NBUCKET * 4;
    int* bucket_base   = (int*)p; p += (size_t)(NBUCKET + 1) * 4;
    int* bucket_cursor = (int*)p; p += (size_t)NBUCKET * 4;

    const int BLK = 256;
    int grid_elem = (int)((TOT_F4 + BLK - 1) / BLK);                 // 18750
    int grid_binA = (nnz + EDGES_PER_BLOCK - 1) / EDGES_PER_BLOCK;   // 782
    int grid_rows = (N_NODES * 64 + BLK - 1) / BLK;                  // 75000

    init_kernel<<<grid_elem, BLK, 0, stream>>>(user, item, (ushort4*)xh);

    // bucket offsets (no per-row global histogram)
    zero_buckets_kernel<<<(NBUCKET + BLK - 1) / BLK, BLK, 0, stream>>>(bucket_count);
    bucket_hist_kernel<<<grid_binA, BLK, 0, stream>>>(rows, bucket_count, nnz);
    bucket_scan_kernel<<<1, 1024, 0, stream>>>(bucket_count, bucket_base, bucket_cursor, nnz);

    // two-pass binned sort into CSR order (binB also emits row_ptr)
    binA_kernel<<<grid_binA, BLK, 0, stream>>>(rows, cols, vals, bucket_cursor, binned, nnz);
    binB_kernel<<<NBUCKET, BLK, 0, stream>>>(bucket_base, binned, sorted, row_ptr, nnz);

    // 3 propagation layers (bf16 state); layer 3 fused with epilogue
    spmm_row_kernel<<<grid_rows, BLK, 0, stream>>>(row_ptr, sorted, xh,  y1h);
    spmm_row_kernel<<<grid_rows, BLK, 0, stream>>>(row_ptr, sorted, y1h, y2h);
    spmm_final_kernel<<<grid_rows, BLK, 0, stream>>>(row_ptr, sorted, y2h, y1h,
                                                     user, item, out);
}

// Round 5
// 786.556 us; speedup vs baseline: 1.1645x; 1.0342x over previous
//
#include <hip/hip_runtime.h>
#include <hip/hip_bf16.h>

#define N_USERS 100000
#define N_ITEMS 200000
#define N_NODES 300000
#define DIM 64

#define TOT_ELEMS ((size_t)N_NODES * DIM)          // 19,200,000 floats
#define TOT_F4    (TOT_ELEMS / 4)                  // 4,800,000
#define USER_F4   (((size_t)N_USERS * DIM) / 4)    // 1,600,000

#define BROWS 512
#define NBUCKET ((N_NODES + BROWS - 1) / BROWS)    // 586
#define EPT 32
#define EDGES_PER_BLOCK (EPT * 256)                // 8192

typedef float        f4_native __attribute__((ext_vector_type(4)));
typedef unsigned int u4_native __attribute__((ext_vector_type(4)));

__device__ __forceinline__ float bf2f(unsigned short u) {
    return __uint_as_float((unsigned int)u << 16);
}
__device__ __forceinline__ unsigned short f2bf(float f) {
    __hip_bfloat16 h = __float2bfloat16(f);   // RNE
    return *reinterpret_cast<unsigned short*>(&h);
}
__device__ __forceinline__ float lo_bf(unsigned int u) {   // low ushort -> f32
    return __uint_as_float(u << 16);
}
__device__ __forceinline__ float hi_bf(unsigned int u) {   // high ushort -> f32
    return __uint_as_float(u & 0xFFFF0000u);
}

// ---------- init: xh = bf16(concat(user,item)) ----------
__global__ void init_kernel(const float* __restrict__ user,
                            const float* __restrict__ item,
                            ushort4* __restrict__ xh) {
    size_t i = (size_t)blockIdx.x * blockDim.x + threadIdx.x;
    if (i >= TOT_F4) return;
    f4_native v = (i < USER_F4)
        ? __builtin_nontemporal_load((const f4_native*)user + i)
        : __builtin_nontemporal_load((const f4_native*)item + (i - USER_F4));
    ushort4 h;
    h.x = f2bf(v.x); h.y = f2bf(v.y); h.z = f2bf(v.z); h.w = f2bf(v.w);
    xh[i] = h;   // cached: gather source of layer 1
}

// ---------- bucket-level histogram (586 counters, cache-resident) ----------
__global__ void zero_buckets_kernel(int* __restrict__ bucket_count) {
    int i = blockIdx.x * blockDim.x + threadIdx.x;
    if (i < NBUCKET) bucket_count[i] = 0;
}

__global__ void bucket_hist_kernel(const int* __restrict__ rows,
                                   int* __restrict__ bucket_count, int nnz) {
    __shared__ int h[NBUCKET];
    int t = threadIdx.x;
    size_t base = (size_t)blockIdx.x * EDGES_PER_BLOCK;
    for (int i = t; i < NBUCKET; i += 256) h[i] = 0;
    __syncthreads();
    #pragma unroll 4
    for (int k = 0; k < EPT; ++k) {
        size_t e = base + (size_t)k * 256 + t;
        if (e < (size_t)nnz) atomicAdd(&h[rows[e] >> 9], 1);
    }
    __syncthreads();
    for (int i = t; i < NBUCKET; i += 256) {
        int c = h[i];
        if (c) atomicAdd(&bucket_count[i], c);
    }
}

// exclusive scan of bucket counts -> bucket_base[0..NBUCKET], seed bucket_cursor
__global__ void bucket_scan_kernel(const int* __restrict__ bucket_count,
                                   int* __restrict__ bucket_base,
                                   int* __restrict__ bucket_cursor, int nnz) {
    __shared__ int s[1024];
    int t = threadIdx.x;
    int orig = (t < NBUCKET) ? bucket_count[t] : 0;
    s[t] = orig;
    __syncthreads();
    for (int off = 1; off < 1024; off <<= 1) {
        int v = (t >= off) ? s[t - off] : 0;
        __syncthreads();
        s[t] += v;
        __syncthreads();
    }
    if (t < NBUCKET) {
        int excl = s[t] - orig;
        bucket_base[t]   = excl;
        bucket_cursor[t] = excl;
    }
    if (t == 0) bucket_base[NBUCKET] = nnz;
}

// ---------- Pass A: LDS counting-sort per block, then coalesced write-out ----
__global__ void binA_kernel(const int* __restrict__ rows,
                            const int* __restrict__ cols,
                            const float* __restrict__ vals,
                            int* __restrict__ bucket_cursor,
                            int2* __restrict__ binned,
                            int nnz) {
    __shared__ int  h[NBUCKET];       // per-bucket counts
    __shared__ int  lstart[NBUCKET];  // local exclusive starts
    __shared__ int  lcur[NBUCKET];    // staging cursors
    __shared__ int  gbase[NBUCKET];   // reserved global bases
    __shared__ int  s[256];           // scan temp
    __shared__ int2 ledge[EDGES_PER_BLOCK];   // 64 KB staging

    int t = threadIdx.x;
    size_t base = (size_t)blockIdx.x * EDGES_PER_BLOCK;
    int nvalid = (int)(((size_t)nnz - base < (size_t)EDGES_PER_BLOCK)
                       ? ((size_t)nnz - base) : (size_t)EDGES_PER_BLOCK);

    for (int i = t; i < NBUCKET; i += 256) h[i] = 0;
    __syncthreads();

    // phase 1: local bucket histogram
    #pragma unroll 4
    for (int k = 0; k < EPT; ++k) {
        int e = k * 256 + t;
        if (e < nvalid) atomicAdd(&h[rows[base + e] >> 9], 1);
    }
    __syncthreads();

    // phase 2: exclusive scan of 586 counts (3 per thread + 256-wide HS scan)
    int i0 = 3 * t, i1 = 3 * t + 1, i2 = 3 * t + 2;
    int c0 = (i0 < NBUCKET) ? h[i0] : 0;
    int c1 = (i1 < NBUCKET) ? h[i1] : 0;
    int c2 = (i2 < NBUCKET) ? h[i2] : 0;
    int g = c0 + c1 + c2;
    s[t] = g;
    __syncthreads();
    for (int off = 1; off < 256; off <<= 1) {
        int v = (t >= off) ? s[t - off] : 0;
        __syncthreads();
        s[t] += v;
        __syncthreads();
    }
    int excl = s[t] - g;
    if (i0 < NBUCKET) { lstart[i0] = excl;           lcur[i0] = excl; }
    if (i1 < NBUCKET) { lstart[i1] = excl + c0;      lcur[i1] = excl + c0; }
    if (i2 < NBUCKET) { lstart[i2] = excl + c0 + c1; lcur[i2] = excl + c0 + c1; }

    // phase 3: reserve global space per bucket
    for (int i = t; i < NBUCKET; i += 256) {
        int c = h[i];
        gbase[i] = c ? atomicAdd(&bucket_cursor[i], c) : 0;
    }
    __syncthreads();   // covers lstart/lcur/gbase before use

    // phase 4: stage edges into LDS, sorted by bucket
    #pragma unroll 4
    for (int k = 0; k < EPT; ++k) {
        int e = k * 256 + t;
        if (e < nvalid) {
            size_t ge = base + e;
            int r = rows[ge];
            int c = __builtin_nontemporal_load(cols + ge);
            float v = __builtin_nontemporal_load(vals + ge);
            int slot = atomicAdd(&lcur[r >> 9], 1);
            ledge[slot] = make_int2(((r & (BROWS - 1)) << 19) | c,
                                    __float_as_int(v));
        }
    }
    __syncthreads();

    // phase 5: slot-major coalesced write-out; bucket via binary search
    for (int slot = t; slot < nvalid; slot += 256) {
        int lo = 0, hi = NBUCKET;
        while (hi - lo > 1) {
            int mid = (lo + hi) >> 1;
            if (lstart[mid] <= slot) lo = mid; else hi = mid;
        }
        binned[gbase[lo] + (slot - lstart[lo])] = ledge[slot];
    }
}

// ---------- Pass B: per-row histogram + scan -> row_ptr, then permute ----------
__global__ void binB_kernel(const int* __restrict__ bucket_base,
                            const int2* __restrict__ binned,
                            int2* __restrict__ sorted,
                            int* __restrict__ row_ptr,
                            int nnz) {
    __shared__ int cnt[BROWS];
    __shared__ int cur[BROWS];
    __shared__ int s[256];
    int b = blockIdx.x, t = threadIdx.x;
    int beg = bucket_base[b];
    int end = bucket_base[b + 1];
    int row0 = b * BROWS;
    for (int i = t; i < BROWS; i += 256) cnt[i] = 0;
    __syncthreads();
    for (int idx = beg + t; idx < end; idx += 256) {
        int lr = ((unsigned)binned[idx].x) >> 19;
        atomicAdd(&cnt[lr], 1);
    }
    __syncthreads();
    int c0 = cnt[2 * t], c1 = cnt[2 * t + 1];
    int local = c0 + c1;
    s[t] = local;
    __syncthreads();
    for (int off = 1; off < 256; off <<= 1) {
        int v = (t >= off) ? s[t - off] : 0;
        __syncthreads();
        s[t] += v;
        __syncthreads();
    }
    int excl = beg + s[t] - local;
    int r0 = row0 + 2 * t;
    if (r0 < N_NODES)     row_ptr[r0]     = excl;
    if (r0 + 1 < N_NODES) row_ptr[r0 + 1] = excl + c0;
    cur[2 * t]     = excl;
    cur[2 * t + 1] = excl + c0;
    __syncthreads();
    for (int idx = beg + t; idx < end; idx += 256) {
        int2 e = binned[idx];
        int lr  = ((unsigned)e.x) >> 19;
        int col = e.x & 0x7FFFF;
        int pos = atomicAdd(&cur[lr], 1);
        sorted[pos] = make_int2(col, e.y);
    }
    if (b == 0 && t == 0) row_ptr[N_NODES] = nnz;
}

// ---------- row accumulate: 8 rows per wave, 8 lanes per row ----------
// Lane l: row = w*8 + (l>>3), dim-chunk e7 = l&7 (dims 8e7..8e7+7, 16B of the
// 128B row). Batches of 8 edges/row in registers; per step one ds_bpermute
// pair broadcasts edge j's (col,val) within each 8-lane group, one
// global_load_dwordx4 fetches 16B/lane (wave = 8 full rows, coalesced per
// group). Per 8 edges: 2 DS + 1 VMEM + ~18 VALU; no cross-lane reduction.
// Masked slots (past row end) broadcast v=0, c=0 (harmless cached fetch).
__device__ __forceinline__ void row_accum8(int beg, int end, int l,
                                           const int2* __restrict__ sorted,
                                           const unsigned short* __restrict__ srch,
                                           float* acc) {
    const int e7   = l & 7;
    const int idxb = (l & ~7) << 2;          // bpermute byte base of group
    const uint4* __restrict__ src4 = (const uint4*)srch;

    int len = end - beg;
    int m = len;
    m = max(m, __shfl_xor(m, 8));
    m = max(m, __shfl_xor(m, 16));
    m = max(m, __shfl_xor(m, 32));
    int nb = (m + 7) >> 3;                   // batches (wave-uniform)
    if (nb <= 0) return;

    int cc = 0, vc = 0;
    {   // batch 0
        int e = beg + e7;
        if (e < end) {
            unsigned long long ed = __builtin_nontemporal_load(
                (const unsigned long long*)sorted + e);
            cc = (int)(unsigned int)(ed & 0xFFFFFFFFull);
            vc = (int)(unsigned int)(ed >> 32);
        }
    }
    for (int b = 0; b < nb; ++b) {
        int cn = 0, vn = 0;
        if (b + 1 < nb) {                    // prefetch next batch
            int e = beg + ((b + 1) << 3) + e7;
            if (e < end) {
                unsigned long long ed = __builtin_nontemporal_load(
                    (const unsigned long long*)sorted + e);
                cn = (int)(unsigned int)(ed & 0xFFFFFFFFull);
                vn = (int)(unsigned int)(ed >> 32);
            }
        }
        #pragma unroll
        for (int j = 0; j < 8; ++j) {
            int   c = __builtin_amdgcn_ds_bpermute(idxb + (j << 2), cc);
            float v = __int_as_float(__builtin_amdgcn_ds_bpermute(idxb + (j << 2), vc));
            uint4 u = src4[(size_t)(((unsigned)c << 3) | (unsigned)e7)];
            acc[0] = fmaf(v, lo_bf(u.x), acc[0]);
            acc[1] = fmaf(v, hi_bf(u.x), acc[1]);
            acc[2] = fmaf(v, lo_bf(u.y), acc[2]);
            acc[3] = fmaf(v, hi_bf(u.y), acc[3]);
            acc[4] = fmaf(v, lo_bf(u.z), acc[4]);
            acc[5] = fmaf(v, hi_bf(u.z), acc[5]);
            acc[6] = fmaf(v, lo_bf(u.w), acc[6]);
            acc[7] = fmaf(v, hi_bf(u.w), acc[7]);
        }
        cc = cn; vc = vn;
    }
}

// ---------- SpMM layers 1&2: bf16 in, bf16 out (dwordx4 store) ----------
__global__ void spmm_row_kernel(const int* __restrict__ row_ptr,
                                const int2* __restrict__ sorted,
                                const unsigned short* __restrict__ srch,
                                unsigned short* __restrict__ dsth) {
    int t = blockIdx.x * blockDim.x + threadIdx.x;
    int w = t >> 6;
    int l = t & 63;
    int r = w * 8 + (l >> 3);
    if (r >= N_NODES) return;                // never taken: 300000 % 8 == 0
    float acc[8] = {0.f, 0.f, 0.f, 0.f, 0.f, 0.f, 0.f, 0.f};
    row_accum8(row_ptr[r], row_ptr[r + 1], l, sorted, srch, acc);
    uint4 o;
    o.x = (unsigned)f2bf(acc[0]) | ((unsigned)f2bf(acc[1]) << 16);
    o.y = (unsigned)f2bf(acc[2]) | ((unsigned)f2bf(acc[3]) << 16);
    o.z = (unsigned)f2bf(acc[4]) | ((unsigned)f2bf(acc[5]) << 16);
    o.w = (unsigned)f2bf(acc[6]) | ((unsigned)f2bf(acc[7]) << 16);
    ((uint4*)dsth)[(size_t)r * 8 + (l & 7)] = o;   // cached: next gather src
}

// ---------- SpMM layer 3 fused with epilogue ----------
// out = 0.25*(emb_f32 + y1 + y2 + acc3); acc3 stays f32 (never bf16-rounded)
__global__ void spmm_final_kernel(const int* __restrict__ row_ptr,
                                  const int2* __restrict__ sorted,
                                  const unsigned short* __restrict__ y2h,  // gather src
                                  const unsigned short* __restrict__ y1h,
                                  const float* __restrict__ user,
                                  const float* __restrict__ item,
                                  float* __restrict__ out) {
    int t = blockIdx.x * blockDim.x + threadIdx.x;
    int w = t >> 6;
    int l = t & 63;
    int r = w * 8 + (l >> 3);
    if (r >= N_NODES) return;
    float acc[8] = {0.f, 0.f, 0.f, 0.f, 0.f, 0.f, 0.f, 0.f};
    row_accum8(row_ptr[r], row_ptr[r + 1], l, sorted, y2h, acc);

    int e7 = l & 7;
    size_t q4 = (size_t)r * 8 + e7;                 // uint4 units (bf16 rows)
    u4_native y1q = __builtin_nontemporal_load((const u4_native*)y1h + q4);
    u4_native y2q = __builtin_nontemporal_load((const u4_native*)y2h + q4);
    size_t fidx = (size_t)r * 16 + 2 * e7;          // float4 units (f32 rows)
    const f4_native* bp = (r < N_USERS)
        ? ((const f4_native*)user + fidx)
        : ((const f4_native*)item + (fidx - (size_t)N_USERS * 16));
    f4_native b0 = __builtin_nontemporal_load(bp);
    f4_native b1 = __builtin_nontemporal_load(bp + 1);
    f4_native o0, o1;
    o0.x = 0.25f * (b0.x + lo_bf(y1q.x) + lo_bf(y2q.x) + acc[0]);
    o0.y = 0.25f * (b0.y + hi_bf(y1q.x) + hi_bf(y2q.x) + acc[1]);
    o0.z = 0.25f * (b0.z + lo_bf(y1q.y) + lo_bf(y2q.y) + acc[2]);
    o0.w = 0.25f * (b0.w + hi_bf(y1q.y) + hi_bf(y2q.y) + acc[3]);
    o1.x = 0.25f * (b1.x + lo_bf(y1q.z) + lo_bf(y2q.z) + acc[4]);
    o1.y = 0.25f * (b1.y + hi_bf(y1q.z) + hi_bf(y2q.z) + acc[5]);
    o1.z = 0.25f * (b1.z + lo_bf(y1q.w) + lo_bf(y2q.w) + acc[6]);
    o1.w = 0.25f * (b1.w + hi_bf(y1q.w) + hi_bf(y2q.w) + acc[7]);
    __builtin_nontemporal_store(o0, (f4_native*)out + fidx);
    __builtin_nontemporal_store(o1, (f4_native*)out + fidx + 1);
}

extern "C" void kernel_launch(void* const* d_in, const int* in_sizes, int n_in,
                              void* d_out, int out_size, void* d_ws, size_t ws_size,
                              hipStream_t stream) {
    const float* user = (const float*)d_in[0];
    const float* item = (const float*)d_in[1];
    const int*   rows = (const int*)d_in[2];
    const int*   cols = (const int*)d_in[3];
    const float* vals = (const float*)d_in[4];
    int nnz = in_sizes[2];

    float* out = (float*)d_out;

    // workspace layout (all offsets multiples of 16)
    char* p = (char*)d_ws;
    unsigned short* xh  = (unsigned short*)p; p += TOT_ELEMS * 2;    // 38.4 MB
    unsigned short* y1h = (unsigned short*)p; p += TOT_ELEMS * 2;    // 38.4 MB
    unsigned short* y2h = (unsigned short*)p; p += TOT_ELEMS * 2;    // 38.4 MB
    int2* binned = (int2*)p; p += (size_t)nnz * sizeof(int2);        // 51.2 MB
    int2* sorted = (int2*)p; p += (size_t)nnz * sizeof(int2);        // 51.2 MB
    int* row_ptr       = (int*)p; p += (size_t)(N_NODES + 1) * 4;
    int* bucket_count  = (int*)p; p += (size_t)NBUCKET * 4;
    int* bucket_base   = (int*)p; p += (size_t)(NBUCKET + 1) * 4;
    int* bucket_cursor = (int*)p; p += (size_t)NBUCKET * 4;

    const int BLK = 256;
    int grid_elem = (int)((TOT_F4 + BLK - 1) / BLK);                 // 18750
    int grid_binA = (nnz + EDGES_PER_BLOCK - 1) / EDGES_PER_BLOCK;   // 782
    int grid_spmm = (int)(((size_t)(N_NODES / 8) * 64 + BLK - 1) / BLK);  // 9375

    init_kernel<<<grid_elem, BLK, 0, stream>>>(user, item, (ushort4*)xh);

    // bucket offsets (no per-row global histogram)
    zero_buckets_kernel<<<(NBUCKET + BLK - 1) / BLK, BLK, 0, stream>>>(bucket_count);
    bucket_hist_kernel<<<grid_binA, BLK, 0, stream>>>(rows, bucket_count, nnz);
    bucket_scan_kernel<<<1, 1024, 0, stream>>>(bucket_count, bucket_base, bucket_cursor, nnz);

    // two-pass binned sort into CSR order (binB also emits row_ptr)
    binA_kernel<<<grid_binA, BLK, 0, stream>>>(rows, cols, vals, bucket_cursor, binned, nnz);
    binB_kernel<<<NBUCKET, BLK, 0, stream>>>(bucket_base, binned, sorted, row_ptr, nnz);

    // 3 propagation layers (bf16 state); layer 3 fused with epilogue
    spmm_row_kernel<<<grid_spmm, BLK, 0, stream>>>(row_ptr, sorted, xh,  y1h);
    spmm_row_kernel<<<grid_spmm, BLK, 0, stream>>>(row_ptr, sorted, y1h, y2h);
    spmm_final_kernel<<<grid_spmm, BLK, 0, stream>>>(row_ptr, sorted, y2h, y1h,
                                                     user, item, out);
}